// Round 12
// baseline (136.732 us; speedup 1.0000x reference)
//
#include <hip/hip_runtime.h>
#include <cstddef>
#include <cstdint>

// B=256, N=32, F=40, H=M=100, EF=4, OUT=128, 3 passes.
#define B_   256
#define N_   32
#define F_   40
#define H_   100
#define OUT_ 128
#define CAP_ 8
#define TB   1024         // 16 waves/block -> 4 waves/SIMD, 1 block/CU
#define XCS  168          // Xcat row stride (shorts)
#define XMS  136          // Xm / Xy row stride (shorts)
#define NBLK 343
#define NLO  63           // readout blocks (280..342) carry lo fragments

using bf16x8 = __attribute__((ext_vector_type(8))) short;   // 8 bf16 (4 VGPRs)
using f32x4  = __attribute__((ext_vector_type(4))) float;   // MFMA C/D

__device__ __forceinline__ float sigmoidf_(float x){ return 1.0f/(1.0f+__expf(-x)); }
__device__ __forceinline__ float bf2f(short s){ return __uint_as_float(((uint32_t)(uint16_t)s)<<16); }
__device__ __forceinline__ short f2bf(float x){            // round-to-nearest-even
  uint32_t u = __float_as_uint(x);
  return (short)((u + 0x7FFFu + ((u>>16)&1u))>>16);
}
__device__ __forceinline__ void bsplit(float x, short& hi, short& lo){
  hi = f2bf(x);
  lo = f2bf(x - bf2f(hi));
}

// ---------------------------------------------------------------------------
// Weight pre-pack (unchanged from R11): dense hi-only 1 KB blocks + separate
// lo region for readout. Coalesced reads, scattered 2B writes.
// ---------------------------------------------------------------------------
__global__ void prep_frags2(const float* __restrict__ Wmsg,
                            const float* __restrict__ Wih,
                            const float* __restrict__ Whh,
                            const float* __restrict__ Wg,
                            const float* __restrict__ We,
                            short* __restrict__ AFhi,
                            short* __restrict__ AFlo){
  int i = blockIdx.x*blockDim.x + threadIdx.x;
  if (i < 40000){                               // W_msg
    float v = Wmsg[i];
    int t = i&3, mk = i>>2, h = mk%100, m = mk/100;
    int blk = t*28 + (m>>4)*4 + (h>>5);
    int lane = (m&15) + (((h&31)>>3)<<4);
    AFhi[(size_t)blk*512 + lane*8 + (h&7)] = f2bf(v);
  } else if (i < 70000){                        // W_ih
    int i2 = i-40000;
    float v = Wih[i2];
    int jrow = i2/100, k = i2%100, mat = jrow/100, mg = jrow%100;
    int blk = 112 + mat*28 + (mg>>4)*4 + (k>>5);
    int lane = (mg&15) + (((k&31)>>3)<<4);
    AFhi[(size_t)blk*512 + lane*8 + (k&7)] = f2bf(v);
  } else if (i < 100000){                       // W_hh
    int i2 = i-70000;
    float v = Whh[i2];
    int jrow = i2/100, k = i2%100, mat = 3 + jrow/100, mg = jrow%100;
    int blk = 112 + mat*28 + (mg>>4)*4 + (k>>5);
    int lane = (mg&15) + (((k&31)>>3)<<4);
    AFhi[(size_t)blk*512 + lane*8 + (k&7)] = f2bf(v);
  } else if (i < 114000){                       // Wg (140x100), hi+lo
    int i2 = i-100000;
    float v = Wg[i2];
    int k = i2/100, j = i2%100;
    int blk = 280 + (j>>4)*5 + (k>>5);
    int lane = (j&15) + (((k&31)>>3)<<4);
    short hi,lo; bsplit(v,hi,lo);
    AFhi[(size_t)blk*512 + lane*8 + (k&7)] = hi;
    AFlo[(size_t)(blk-280)*512 + lane*8 + (k&7)] = lo;
  } else if (i < 124000){                       // We (100x100), hi+lo
    int i2 = i-114000;
    float v = We[i2];
    int k = i2/100, j = i2%100;
    int blk = 315 + (j>>4)*4 + (k>>5);
    int lane = (j&15) + (((k&31)>>3)<<4);
    short hi,lo; bsplit(v,hi,lo);
    AFhi[(size_t)blk*512 + lane*8 + (k&7)] = hi;
    AFlo[(size_t)(blk-280)*512 + lane*8 + (k&7)] = lo;
  }
}

// B-operand fragment from LDS [n][k] bf16: lane holds B[k=(lane>>4)*8+j][n=lane&15]
__device__ __forceinline__ bf16x8 ldB(const short* X, int stride, int nt, int ks, int lane){
  int n = nt*16 + (lane&15);
  return *(const bf16x8*)&X[n*stride + ks*32 + (lane>>4)*8];
}
__device__ __forceinline__ bf16x8 ldA(const short* __restrict__ AFhi, int blk, int lane){
  return *(const bf16x8*)(AFhi + (size_t)blk*512 + lane*8);
}
// C += A*(Bhi+Blo) with a pre-loaded A fragment
__device__ __forceinline__ f32x4 mm2f(bf16x8 ah, bf16x8 bh, bf16x8 bl, f32x4 c){
  c = __builtin_amdgcn_mfma_f32_16x16x32_bf16(ah, bh, c, 0,0,0);
  c = __builtin_amdgcn_mfma_f32_16x16x32_bf16(ah, bl, c, 0,0,0);
  return c;
}

// ---------------------------------------------------------------------------
// Fused MPNN, one block per batch, 1024 threads (16 waves), 14 tile-tasks.
// 3 barriers/pass. All mm loops: #pragma unroll 1 (spill guard) + rolling
// DEPTH-2 PREFETCH of A (global, ~200cyc) and B (LDS, ~120cyc) — R11 showed
// the unroll-1 chains were latency-bound (load->waitcnt->mfma serialization),
// not MFMA- or bandwidth-bound.
// ---------------------------------------------------------------------------
__global__ __launch_bounds__(TB, 4) void mpnn_mfma(
    const float* __restrict__ nodes, const float* __restrict__ edges,
    const short* __restrict__ AFhi, const short* __restrict__ AFlo,
    const float* __restrict__ b_ih, const float* __restrict__ b_hh,
    const float* __restrict__ bg, const float* __restrict__ be,
    const float* __restrict__ Wo, const float* __restrict__ bo,
    float* __restrict__ out){
  const int b = blockIdx.x;
  const int tid = threadIdx.x;
  const int lane = tid & 63;
  const int w = tid >> 6;

  __shared__ short XcH[32*XCS], XcL[32*XCS];      // cat: h | nodes(100..139) | 0
  __shared__ short XmH[32*XMS], XmL[32*XMS];      // messages
  __shared__ short XyH[4][32*XMS], XyL[4][32*XMS];// per-type aggregated Y_t
  __shared__ float sh_ge[H_];
  __shared__ float sh_part[4][OUT_];              // Wo-tail partials
  __shared__ float sh_rowsum[N_];
  __shared__ int   sh_cnt[N_];
  __shared__ int   sh_gt[N_][CAP_];               // packed (g<<2)|t
  __shared__ float sh_w[N_][CAP_];

  // ---- zero LDS (Xc rows>=140 and Xm rows>=100 must stay 0) ----------------
  for (int i=tid;i<(32*XCS)/2;i+=TB){ ((int*)XcH)[i]=0; ((int*)XcL)[i]=0; }
  for (int i=tid;i<(32*XMS)/2;i+=TB){ ((int*)XmH)[i]=0; ((int*)XmL)[i]=0; }
  if (tid < H_) sh_ge[tid]=0.0f;
  if (tid < N_){ sh_cnt[tid]=0; sh_rowsum[tid]=0.0f; }
  __syncthreads();

  // ---- per-node neighbor lists + node staging ------------------------------
  for (int p=tid; p<N_*N_; p+=TB){
    int n = p>>5, g = p&31;
    const float4 ev = *(const float4*)(edges + (((size_t)b*N_+n)*N_+g)*4);
    float adj = ev.x+ev.y+ev.z+ev.w;
    if (adj != 0.0f){
      atomicAdd(&sh_rowsum[n], adj);
      float ef[4] = {ev.x,ev.y,ev.z,ev.w};
      for (int f=0; f<4; ++f)
        if (ef[f] != 0.0f){
          int s = atomicAdd(&sh_cnt[n],1);
          if (s<CAP_){ sh_gt[n][s]=(g<<2)|f; sh_w[n][s]=ef[f]; }
        }
    }
  }
  for (int p=tid; p<N_*F_; p+=TB){
    int n = p/F_, f = p%F_;
    float x = nodes[((size_t)b*N_+n)*F_ + f];
    short hi,lo; bsplit(x,hi,lo);
    XcH[n*XCS+f]=hi;      XcL[n*XCS+f]=lo;        // h init rows 0..39
    XcH[n*XCS+100+f]=hi;  XcL[n*XCS+100+f]=lo;    // cat-tail rows 100..139
  }
  __syncthreads();

  const int jmt = w>>1, nt = w&1;                 // task (w<14)
  const bool task = (w < 14);

  for (int pass=0; pass<3; ++pass){
    // ---- build ALL Y_t in one sweep: n wave-uniform, lanes along k ---------
    for (int it=0; it<2; ++it){
      int idx = tid + it*TB;                   // 0..2047
      int n = idx >> 6;                        // wave-uniform
      int kp = idx & 63;                       // int index: k = 2kp, 2kp+1
      int cnt = sh_cnt[n] < CAP_ ? sh_cnt[n] : CAP_;
      float s0[4]={0,0,0,0}, s1[4]={0,0,0,0};
      for (int e=0;e<cnt;++e){
        int gt = sh_gt[n][e];                  // wave-uniform -> scalar branch
        int g = gt>>2; float wv = sh_w[n][e];
        int hh = ((const int*)(XcH + g*XCS))[kp];
        int ll = ((const int*)(XcL + g*XCS))[kp];
        float h0 = bf2f((short)(hh&0xffff)) + bf2f((short)(ll&0xffff));
        float h1 = bf2f((short)(hh>>16))    + bf2f((short)(ll>>16));
        int t = gt&3;
        if (t==0)      { s0[0]+=wv*h0; s1[0]+=wv*h1; }
        else if (t==1) { s0[1]+=wv*h0; s1[1]+=wv*h1; }
        else if (t==2) { s0[2]+=wv*h0; s1[2]+=wv*h1; }
        else           { s0[3]+=wv*h0; s1[3]+=wv*h1; }
      }
#pragma unroll
      for (int t=0;t<4;++t){
        short a,b2,c,d; bsplit(s0[t],a,b2); bsplit(s1[t],c,d);
        ((int*)(XyH[t] + n*XMS))[kp] = (int)((uint16_t)a  | ((uint32_t)(uint16_t)c<<16));
        ((int*)(XyL[t] + n*XMS))[kp] = (int)((uint16_t)b2 | ((uint32_t)(uint16_t)d<<16));
      }
    }
    __syncthreads();
    // ---- region 1: messages mm2 (prefetched) + hh mm2 (prefetched) ---------
    f32x4 Ch0=(f32x4)0.0f, Ch1=(f32x4)0.0f, Ch2=(f32x4)0.0f;
    if (task){
      f32x4 Cm0=(f32x4)0.0f, Cm1=(f32x4)0.0f;
      {
        bf16x8 ah = ldA(AFhi, jmt*4, lane);
        bf16x8 bh = ldB(XyH[0],XMS,nt,0,lane), bl = ldB(XyL[0],XMS,nt,0,lane);
#pragma unroll 1
        for (int i=0;i<16;++i){
          int ip = (i<15)? i+1 : 15;
          int tp = ip>>2, ksp = ip&3;
          bf16x8 an  = ldA(AFhi, (tp*7+jmt)*4+ksp, lane);
          bf16x8 bhn = ldB(XyH[tp],XMS,nt,ksp,lane);
          bf16x8 bln = ldB(XyL[tp],XMS,nt,ksp,lane);
          if (i<8) Cm0 = mm2f(ah, bh, bl, Cm0);
          else     Cm1 = mm2f(ah, bh, bl, Cm1);
          ah = an; bh = bhn; bl = bln;
        }
      }
      {
        bf16x8 ah = ldA(AFhi, 112+3*28+jmt*4, lane);
        bf16x8 bh = ldB(XcH,XCS,nt,0,lane), bl = ldB(XcL,XCS,nt,0,lane);
#pragma unroll 1
        for (int i=0;i<12;++i){
          int ip = (i<11)? i+1 : 11;
          int gp = ip>>2, ksp = ip&3;
          bf16x8 an  = ldA(AFhi, 112+(gp+3)*28+jmt*4+ksp, lane);
          bf16x8 bhn = ldB(XcH,XCS,nt,ksp,lane);
          bf16x8 bln = ldB(XcL,XCS,nt,ksp,lane);
          int g = i>>2;
          if (g==0)      Ch0 = mm2f(ah, bh, bl, Ch0);
          else if (g==1) Ch1 = mm2f(ah, bh, bl, Ch1);
          else           Ch2 = mm2f(ah, bh, bl, Ch2);
          ah = an; bh = bhn; bl = bln;
        }
      }
      f32x4 Cm = Cm0 + Cm1;
      int n = nt*16+(lane&15);                 // Xm write (disjoint from Xy/Xc)
      for (int r=0;r<4;++r){
        int row = jmt*16 + (lane>>4)*4 + r;
        if (row<100){
          short hi,lo; bsplit(Cm[r],hi,lo);
          XmH[n*XMS+row]=hi; XmL[n*XMS+row]=lo;
        }
      }
    }
    __syncthreads();
    // ---- region 2: ih mm2 (prefetched) + GRU elementwise -------------------
    if (task){
      f32x4 Ci0=(f32x4)0.0f, Ci1=(f32x4)0.0f, Ci2=(f32x4)0.0f;
      {
        bf16x8 ah = ldA(AFhi, 112+jmt*4, lane);
        bf16x8 bh = ldB(XmH,XMS,nt,0,lane), bl = ldB(XmL,XMS,nt,0,lane);
#pragma unroll 1
        for (int i=0;i<12;++i){
          int ip = (i<11)? i+1 : 11;
          int gp = ip>>2, ksp = ip&3;
          bf16x8 an  = ldA(AFhi, 112+gp*28+jmt*4+ksp, lane);
          bf16x8 bhn = ldB(XmH,XMS,nt,ksp,lane);
          bf16x8 bln = ldB(XmL,XMS,nt,ksp,lane);
          int g = i>>2;
          if (g==0)      Ci0 = mm2f(ah, bh, bl, Ci0);
          else if (g==1) Ci1 = mm2f(ah, bh, bl, Ci1);
          else           Ci2 = mm2f(ah, bh, bl, Ci2);
          ah = an; bh = bhn; bl = bln;
        }
      }
      int n = nt*16+(lane&15);
      bool msk = (sh_rowsum[n] != 0.0f);
      for (int r=0;r<4;++r){
        int row = jmt*16 + (lane>>4)*4 + r;
        if (row<100){
          float ho = bf2f(XcH[n*XCS+row]) + bf2f(XcL[n*XCS+row]);
          float rr = sigmoidf_(Ci0[r]+Ch0[r] + b_ih[row]     + b_hh[row]);
          float zz = sigmoidf_(Ci1[r]+Ch1[r] + b_ih[100+row] + b_hh[100+row]);
          float nn = tanhf(Ci2[r] + b_ih[200+row] + rr*(Ch2[r] + b_hh[200+row]));
          float hnew = (1.0f-zz)*nn + zz*ho;
          if (!msk) hnew = ho;
          short hi,lo; bsplit(hnew,hi,lo);
          XcH[n*XCS+row]=hi; XcL[n*XCS+row]=lo;
        }
      }
    }
    __syncthreads();
  }

  // ---- readout: gate/emb GEMMs (prefetched, hi+lo A), masked sum -----------
  f32x4 Cg=(f32x4)0.0f, Ce=(f32x4)0.0f;
  if (task){
    // iteration table: i<5 -> Cg blk 280+jmt*5+i (B ks=i)
    //                  i>=5 -> Ce blk 315+jmt*4+(i-5) (B ks=i-5)
    bf16x8 ah = ldA(AFhi, 280+jmt*5, lane);
    bf16x8 al = ldA(AFlo, jmt*5, lane);
    bf16x8 bh = ldB(XcH,XCS,nt,0,lane), bl = ldB(XcL,XCS,nt,0,lane);
#pragma unroll 1
    for (int i=0;i<9;++i){
      int ip = (i<8)? i+1 : 8;
      int blkp  = (ip<5)? 280+jmt*5+ip : 315+jmt*4+(ip-5);
      int blkpl = blkp-280;
      int ksp   = (ip<5)? ip : ip-5;
      bf16x8 an  = ldA(AFhi, blkp, lane);
      bf16x8 aln = ldA(AFlo, blkpl, lane);
      bf16x8 bhn = ldB(XcH,XCS,nt,ksp,lane);
      bf16x8 bln = ldB(XcL,XCS,nt,ksp,lane);
      if (i<5){
        Cg = mm2f(ah, bh, bl, Cg);
        Cg = __builtin_amdgcn_mfma_f32_16x16x32_bf16(al, bh, Cg, 0,0,0);
      } else {
        Ce = mm2f(ah, bh, bl, Ce);
        Ce = __builtin_amdgcn_mfma_f32_16x16x32_bf16(al, bh, Ce, 0,0,0);
      }
      ah = an; al = aln; bh = bhn; bl = bln;
    }
    int n = nt*16+(lane&15);
    bool msk = (sh_rowsum[n] != 0.0f);
    for (int r=0;r<4;++r){
      int row = jmt*16 + (lane>>4)*4 + r;
      float v = 0.0f;
      if (row<100){
        float gate = sigmoidf_(Cg[r] + bg[row]);
        float emb  = gate*(Ce[r] + be[row]);
        v = msk ? emb : 0.0f;
      }
      v += __shfl_xor(v, 1);                   // reduce across 16 cols
      v += __shfl_xor(v, 2);
      v += __shfl_xor(v, 4);
      v += __shfl_xor(v, 8);
      if (row<100 && (lane&15)==0) atomicAdd(&sh_ge[row], v);
    }
  }
  __syncthreads();
  // ---- out = graph_emb @ Wo + bo : 512 threads, 4 k-chunks of 25 -----------
  if (tid < 512){
    int o = tid & 127, q = tid >> 7;           // lanes consecutive in o -> coalesced
    float s = 0.0f;
    int k0 = 25*q;
#pragma unroll 5
    for (int k=k0; k<k0+25; ++k) s += sh_ge[k]*Wo[k*OUT_+o];
    sh_part[q][o] = s;
  }
  __syncthreads();
  if (tid < OUT_){
    out[(size_t)b*OUT_ + tid] = bo[tid] + sh_part[0][tid] + sh_part[1][tid]
                              + sh_part[2][tid] + sh_part[3][tid];
  }
}

extern "C" void kernel_launch(void* const* d_in, const int* in_sizes, int n_in,
                              void* d_out, int out_size, void* d_ws, size_t ws_size,
                              hipStream_t stream){
  const float* nodes = (const float*)d_in[0];
  const float* edges = (const float*)d_in[1];
  const float* W_msg = (const float*)d_in[2];
  const float* W_ih  = (const float*)d_in[3];
  const float* W_hh  = (const float*)d_in[4];
  const float* b_ih  = (const float*)d_in[5];
  const float* b_hh  = (const float*)d_in[6];
  const float* Wg    = (const float*)d_in[7];
  const float* bg    = (const float*)d_in[8];
  const float* We    = (const float*)d_in[9];
  const float* be    = (const float*)d_in[10];
  const float* Wo    = (const float*)d_in[11];
  const float* bo    = (const float*)d_in[12];

  short* AFhi = (short*)d_ws;                        // 343*512 shorts = 343 KB
  short* AFlo = AFhi + (size_t)NBLK*512;             //  63*512 shorts =  63 KB
  size_t af_bytes = ((size_t)NBLK + NLO) * 512 * sizeof(short);

  hipMemsetAsync(d_ws, 0, af_bytes, stream);         // zero OOR fragment slots
  prep_frags2<<<(124000 + 255)/256, 256, 0, stream>>>(W_msg, W_ih, W_hh, Wg, We,
                                                      AFhi, AFlo);
  mpnn_mfma<<<B_, TB, 0, stream>>>(nodes, edges, AFhi, AFlo, b_ih, b_hh, bg, be,
                                   Wo, bo, (float*)d_out);
}

// Round 13
// 133.884 us; speedup vs baseline: 1.0213x; 1.0213x over previous
//
#include <hip/hip_runtime.h>
#include <cstddef>
#include <cstdint>

// B=256, N=32, F=40, H=M=100, EF=4, OUT=128, 3 passes.
#define B_   256
#define N_   32
#define F_   40
#define H_   100
#define OUT_ 128
#define CAP_ 8
#define TB   1024         // 16 waves/block -> 4 waves/SIMD, 1 block/CU
#define XCS  168          // Xcat row stride (shorts)
#define XMS  136          // Xm / Xy row stride (shorts)
#define NBLK 343
#define NLO  63           // readout blocks (280..342) carry lo fragments

using bf16x8 = __attribute__((ext_vector_type(8))) short;   // 8 bf16 (4 VGPRs)
using f32x4  = __attribute__((ext_vector_type(4))) float;   // MFMA C/D

__device__ __forceinline__ float sigmoidf_(float x){ return 1.0f/(1.0f+__expf(-x)); }
__device__ __forceinline__ float bf2f(short s){ return __uint_as_float(((uint32_t)(uint16_t)s)<<16); }
__device__ __forceinline__ short f2bf(float x){            // round-to-nearest-even
  uint32_t u = __float_as_uint(x);
  return (short)((u + 0x7FFFu + ((u>>16)&1u))>>16);
}
__device__ __forceinline__ void bsplit(float x, short& hi, short& lo){
  hi = f2bf(x);
  lo = f2bf(x - bf2f(hi));
}

// ---------------------------------------------------------------------------
// Weight pre-pack (unchanged): dense hi-only 1 KB blocks + separate lo region
// for the readout weights. Coalesced reads, scattered 2B writes.
// ---------------------------------------------------------------------------
__global__ void prep_frags2(const float* __restrict__ Wmsg,
                            const float* __restrict__ Wih,
                            const float* __restrict__ Whh,
                            const float* __restrict__ Wg,
                            const float* __restrict__ We,
                            short* __restrict__ AFhi,
                            short* __restrict__ AFlo){
  int i = blockIdx.x*blockDim.x + threadIdx.x;
  if (i < 40000){                               // W_msg
    float v = Wmsg[i];
    int t = i&3, mk = i>>2, h = mk%100, m = mk/100;
    int blk = t*28 + (m>>4)*4 + (h>>5);
    int lane = (m&15) + (((h&31)>>3)<<4);
    AFhi[(size_t)blk*512 + lane*8 + (h&7)] = f2bf(v);
  } else if (i < 70000){                        // W_ih
    int i2 = i-40000;
    float v = Wih[i2];
    int jrow = i2/100, k = i2%100, mat = jrow/100, mg = jrow%100;
    int blk = 112 + mat*28 + (mg>>4)*4 + (k>>5);
    int lane = (mg&15) + (((k&31)>>3)<<4);
    AFhi[(size_t)blk*512 + lane*8 + (k&7)] = f2bf(v);
  } else if (i < 100000){                       // W_hh
    int i2 = i-70000;
    float v = Whh[i2];
    int jrow = i2/100, k = i2%100, mat = 3 + jrow/100, mg = jrow%100;
    int blk = 112 + mat*28 + (mg>>4)*4 + (k>>5);
    int lane = (mg&15) + (((k&31)>>3)<<4);
    AFhi[(size_t)blk*512 + lane*8 + (k&7)] = f2bf(v);
  } else if (i < 114000){                       // Wg (140x100), hi+lo
    int i2 = i-100000;
    float v = Wg[i2];
    int k = i2/100, j = i2%100;
    int blk = 280 + (j>>4)*5 + (k>>5);
    int lane = (j&15) + (((k&31)>>3)<<4);
    short hi,lo; bsplit(v,hi,lo);
    AFhi[(size_t)blk*512 + lane*8 + (k&7)] = hi;
    AFlo[(size_t)(blk-280)*512 + lane*8 + (k&7)] = lo;
  } else if (i < 124000){                       // We (100x100), hi+lo
    int i2 = i-114000;
    float v = We[i2];
    int k = i2/100, j = i2%100;
    int blk = 315 + (j>>4)*4 + (k>>5);
    int lane = (j&15) + (((k&31)>>3)<<4);
    short hi,lo; bsplit(v,hi,lo);
    AFhi[(size_t)blk*512 + lane*8 + (k&7)] = hi;
    AFlo[(size_t)(blk-280)*512 + lane*8 + (k&7)] = lo;
  }
}

// B-operand fragment from LDS [n][k] bf16: lane holds B[k=(lane>>4)*8+j][n=lane&15]
__device__ __forceinline__ bf16x8 ldB(const short* X, int stride, int nt, int ks, int lane){
  int n = nt*16 + (lane&15);
  return *(const bf16x8*)&X[n*stride + ks*32 + (lane>>4)*8];
}
__device__ __forceinline__ bf16x8 ldA(const short* __restrict__ AF, int blk, int lane){
  return *(const bf16x8*)(AF + (size_t)blk*512 + lane*8);
}

// ---------------------------------------------------------------------------
// Fused MPNN, one block per batch, 1024 threads (16 waves), 14 tile-tasks.
// bf16-ONLY GEMM OPERANDS (R12 showed aggregate issue-bound: VALU+LDS+MFMA all
// paying the hi/lo tax). XcL kept ONLY for the GRU state path (ho/hnew) so h
// stays fp32-class across passes; readout A keeps hi+lo for weight precision.
// 3 barriers/pass; depth-2 prefetch; #pragma unroll 1 spill guard throughout.
// ---------------------------------------------------------------------------
__global__ __launch_bounds__(TB, 4) void mpnn_mfma(
    const float* __restrict__ nodes, const float* __restrict__ edges,
    const short* __restrict__ AFhi, const short* __restrict__ AFlo,
    const float* __restrict__ b_ih, const float* __restrict__ b_hh,
    const float* __restrict__ bg, const float* __restrict__ be,
    const float* __restrict__ Wo, const float* __restrict__ bo,
    float* __restrict__ out){
  const int b = blockIdx.x;
  const int tid = threadIdx.x;
  const int lane = tid & 63;
  const int w = tid >> 6;

  __shared__ short XcH[32*XCS], XcL[32*XCS];      // cat: h | nodes(100..139) | 0
  __shared__ short XmH[32*XMS];                   // messages (bf16)
  __shared__ short XyH[4][32*XMS];                // per-type aggregated Y_t (bf16)
  __shared__ float sh_ge[H_];
  __shared__ float sh_part[4][OUT_];              // Wo-tail partials
  __shared__ float sh_rowsum[N_];
  __shared__ int   sh_cnt[N_];
  __shared__ int   sh_gt[N_][CAP_];               // packed (g<<2)|t
  __shared__ float sh_w[N_][CAP_];

  // ---- zero LDS (Xc rows>=140 and Xm rows>=100 must stay 0) ----------------
  for (int i=tid;i<(32*XCS)/2;i+=TB){ ((int*)XcH)[i]=0; ((int*)XcL)[i]=0; }
  for (int i=tid;i<(32*XMS)/2;i+=TB){ ((int*)XmH)[i]=0; }
  if (tid < H_) sh_ge[tid]=0.0f;
  if (tid < N_){ sh_cnt[tid]=0; sh_rowsum[tid]=0.0f; }
  __syncthreads();

  // ---- per-node neighbor lists + node staging ------------------------------
  for (int p=tid; p<N_*N_; p+=TB){
    int n = p>>5, g = p&31;
    const float4 ev = *(const float4*)(edges + (((size_t)b*N_+n)*N_+g)*4);
    float adj = ev.x+ev.y+ev.z+ev.w;
    if (adj != 0.0f){
      atomicAdd(&sh_rowsum[n], adj);
      float ef[4] = {ev.x,ev.y,ev.z,ev.w};
      for (int f=0; f<4; ++f)
        if (ef[f] != 0.0f){
          int s = atomicAdd(&sh_cnt[n],1);
          if (s<CAP_){ sh_gt[n][s]=(g<<2)|f; sh_w[n][s]=ef[f]; }
        }
    }
  }
  for (int p=tid; p<N_*F_; p+=TB){
    int n = p/F_, f = p%F_;
    float x = nodes[((size_t)b*N_+n)*F_ + f];
    short hi,lo; bsplit(x,hi,lo);
    XcH[n*XCS+f]=hi;      XcL[n*XCS+f]=lo;        // h init rows 0..39
    XcH[n*XCS+100+f]=hi;  XcL[n*XCS+100+f]=lo;    // cat-tail rows 100..139
  }
  __syncthreads();

  const int jmt = w>>1, nt = w&1;                 // task (w<14)
  const bool task = (w < 14);

  for (int pass=0; pass<3; ++pass){
    // ---- build ALL Y_t in one sweep (bf16 inputs/outputs) ------------------
    for (int it=0; it<2; ++it){
      int idx = tid + it*TB;                   // 0..2047
      int n = idx >> 6;                        // wave-uniform
      int kp = idx & 63;                       // int index: k = 2kp, 2kp+1
      int cnt = sh_cnt[n] < CAP_ ? sh_cnt[n] : CAP_;
      float s0[4]={0,0,0,0}, s1[4]={0,0,0,0};
      for (int e=0;e<cnt;++e){
        int gt = sh_gt[n][e];                  // wave-uniform -> scalar branch
        int g = gt>>2; float wv = sh_w[n][e];
        int hh = ((const int*)(XcH + g*XCS))[kp];
        float h0 = bf2f((short)(hh&0xffff));
        float h1 = bf2f((short)(hh>>16));
        int t = gt&3;
        if (t==0)      { s0[0]+=wv*h0; s1[0]+=wv*h1; }
        else if (t==1) { s0[1]+=wv*h0; s1[1]+=wv*h1; }
        else if (t==2) { s0[2]+=wv*h0; s1[2]+=wv*h1; }
        else           { s0[3]+=wv*h0; s1[3]+=wv*h1; }
      }
#pragma unroll
      for (int t=0;t<4;++t){
        ((int*)(XyH[t] + n*XMS))[kp] =
          (int)((uint16_t)f2bf(s0[t]) | ((uint32_t)(uint16_t)f2bf(s1[t])<<16));
      }
    }
    __syncthreads();
    // ---- region 1: messages (16 mm1) + hh gates (12 mm1), prefetched -------
    f32x4 Ch0=(f32x4)0.0f, Ch1=(f32x4)0.0f, Ch2=(f32x4)0.0f;
    if (task){
      f32x4 Cm0=(f32x4)0.0f, Cm1=(f32x4)0.0f;
      {
        bf16x8 ah = ldA(AFhi, jmt*4, lane);
        bf16x8 bh = ldB(XyH[0],XMS,nt,0,lane);
#pragma unroll 1
        for (int i=0;i<16;++i){
          int ip = (i<15)? i+1 : 15;
          int tp = ip>>2, ksp = ip&3;
          bf16x8 an  = ldA(AFhi, tp*28+jmt*4+ksp, lane);
          bf16x8 bhn = ldB(XyH[tp],XMS,nt,ksp,lane);
          if (i<8) Cm0 = __builtin_amdgcn_mfma_f32_16x16x32_bf16(ah, bh, Cm0, 0,0,0);
          else     Cm1 = __builtin_amdgcn_mfma_f32_16x16x32_bf16(ah, bh, Cm1, 0,0,0);
          ah = an; bh = bhn;
        }
      }
      {
        bf16x8 ah = ldA(AFhi, 112+3*28+jmt*4, lane);
        bf16x8 bh = ldB(XcH,XCS,nt,0,lane);
#pragma unroll 1
        for (int i=0;i<12;++i){
          int ip = (i<11)? i+1 : 11;
          int gp = ip>>2, ksp = ip&3;
          bf16x8 an  = ldA(AFhi, 112+(gp+3)*28+jmt*4+ksp, lane);
          bf16x8 bhn = ldB(XcH,XCS,nt,ksp,lane);
          int g = i>>2;
          if (g==0)      Ch0 = __builtin_amdgcn_mfma_f32_16x16x32_bf16(ah, bh, Ch0, 0,0,0);
          else if (g==1) Ch1 = __builtin_amdgcn_mfma_f32_16x16x32_bf16(ah, bh, Ch1, 0,0,0);
          else           Ch2 = __builtin_amdgcn_mfma_f32_16x16x32_bf16(ah, bh, Ch2, 0,0,0);
          ah = an; bh = bhn;
        }
      }
      f32x4 Cm = Cm0 + Cm1;
      int n = nt*16+(lane&15);                 // Xm write (disjoint from Xy/Xc)
      for (int r=0;r<4;++r){
        int row = jmt*16 + (lane>>4)*4 + r;
        if (row<100) XmH[n*XMS+row] = f2bf(Cm[r]);
      }
    }
    __syncthreads();
    // ---- region 2: ih gates (12 mm1, prefetched) + GRU elementwise ---------
    if (task){
      f32x4 Ci0=(f32x4)0.0f, Ci1=(f32x4)0.0f, Ci2=(f32x4)0.0f;
      {
        bf16x8 ah = ldA(AFhi, 112+jmt*4, lane);
        bf16x8 bh = ldB(XmH,XMS,nt,0,lane);
#pragma unroll 1
        for (int i=0;i<12;++i){
          int ip = (i<11)? i+1 : 11;
          int gp = ip>>2, ksp = ip&3;
          bf16x8 an  = ldA(AFhi, 112+gp*28+jmt*4+ksp, lane);
          bf16x8 bhn = ldB(XmH,XMS,nt,ksp,lane);
          int g = i>>2;
          if (g==0)      Ci0 = __builtin_amdgcn_mfma_f32_16x16x32_bf16(ah, bh, Ci0, 0,0,0);
          else if (g==1) Ci1 = __builtin_amdgcn_mfma_f32_16x16x32_bf16(ah, bh, Ci1, 0,0,0);
          else           Ci2 = __builtin_amdgcn_mfma_f32_16x16x32_bf16(ah, bh, Ci2, 0,0,0);
          ah = an; bh = bhn;
        }
      }
      int n = nt*16+(lane&15);
      bool msk = (sh_rowsum[n] != 0.0f);
      for (int r=0;r<4;++r){
        int row = jmt*16 + (lane>>4)*4 + r;
        if (row<100){
          float ho = bf2f(XcH[n*XCS+row]) + bf2f(XcL[n*XCS+row]);  // fp32-class state
          float rr = sigmoidf_(Ci0[r]+Ch0[r] + b_ih[row]     + b_hh[row]);
          float zz = sigmoidf_(Ci1[r]+Ch1[r] + b_ih[100+row] + b_hh[100+row]);
          float nn = tanhf(Ci2[r] + b_ih[200+row] + rr*(Ch2[r] + b_hh[200+row]));
          float hnew = (1.0f-zz)*nn + zz*ho;
          if (!msk) hnew = ho;
          short hi,lo; bsplit(hnew,hi,lo);
          XcH[n*XCS+row]=hi; XcL[n*XCS+row]=lo;
        }
      }
    }
    __syncthreads();
  }

  // ---- readout: gate/emb GEMMs (A hi+lo, B bf16, prefetched), masked sum ---
  f32x4 Cg=(f32x4)0.0f, Ce=(f32x4)0.0f;
  if (task){
    bf16x8 ah = ldA(AFhi, 280+jmt*5, lane);
    bf16x8 al = ldA(AFlo, jmt*5, lane);
    bf16x8 bh = ldB(XcH,XCS,nt,0,lane);
#pragma unroll 1
    for (int i=0;i<9;++i){
      int ip = (i<8)? i+1 : 8;
      int blkp  = (ip<5)? 280+jmt*5+ip : 315+jmt*4+(ip-5);
      int ksp   = (ip<5)? ip : ip-5;
      bf16x8 an  = ldA(AFhi, blkp, lane);
      bf16x8 aln = ldA(AFlo, blkp-280, lane);
      bf16x8 bhn = ldB(XcH,XCS,nt,ksp,lane);
      if (i<5){
        Cg = __builtin_amdgcn_mfma_f32_16x16x32_bf16(ah, bh, Cg, 0,0,0);
        Cg = __builtin_amdgcn_mfma_f32_16x16x32_bf16(al, bh, Cg, 0,0,0);
      } else {
        Ce = __builtin_amdgcn_mfma_f32_16x16x32_bf16(ah, bh, Ce, 0,0,0);
        Ce = __builtin_amdgcn_mfma_f32_16x16x32_bf16(al, bh, Ce, 0,0,0);
      }
      ah = an; al = aln; bh = bhn;
    }
    int n = nt*16+(lane&15);
    bool msk = (sh_rowsum[n] != 0.0f);
    for (int r=0;r<4;++r){
      int row = jmt*16 + (lane>>4)*4 + r;
      float v = 0.0f;
      if (row<100){
        float gate = sigmoidf_(Cg[r] + bg[row]);
        float emb  = gate*(Ce[r] + be[row]);
        v = msk ? emb : 0.0f;
      }
      v += __shfl_xor(v, 1);                   // reduce across 16 cols
      v += __shfl_xor(v, 2);
      v += __shfl_xor(v, 4);
      v += __shfl_xor(v, 8);
      if (row<100 && (lane&15)==0) atomicAdd(&sh_ge[row], v);
    }
  }
  __syncthreads();
  // ---- out = graph_emb @ Wo + bo : 512 threads, 4 k-chunks of 25 -----------
  if (tid < 512){
    int o = tid & 127, q = tid >> 7;           // lanes consecutive in o -> coalesced
    float s = 0.0f;
    int k0 = 25*q;
#pragma unroll 5
    for (int k=k0; k<k0+25; ++k) s += sh_ge[k]*Wo[k*OUT_+o];
    sh_part[q][o] = s;
  }
  __syncthreads();
  if (tid < OUT_){
    out[(size_t)b*OUT_ + tid] = bo[tid] + sh_part[0][tid] + sh_part[1][tid]
                              + sh_part[2][tid] + sh_part[3][tid];
  }
}

extern "C" void kernel_launch(void* const* d_in, const int* in_sizes, int n_in,
                              void* d_out, int out_size, void* d_ws, size_t ws_size,
                              hipStream_t stream){
  const float* nodes = (const float*)d_in[0];
  const float* edges = (const float*)d_in[1];
  const float* W_msg = (const float*)d_in[2];
  const float* W_ih  = (const float*)d_in[3];
  const float* W_hh  = (const float*)d_in[4];
  const float* b_ih  = (const float*)d_in[5];
  const float* b_hh  = (const float*)d_in[6];
  const float* Wg    = (const float*)d_in[7];
  const float* bg    = (const float*)d_in[8];
  const float* We    = (const float*)d_in[9];
  const float* be    = (const float*)d_in[10];
  const float* Wo    = (const float*)d_in[11];
  const float* bo    = (const float*)d_in[12];

  short* AFhi = (short*)d_ws;                        // 343*512 shorts = 343 KB
  short* AFlo = AFhi + (size_t)NBLK*512;             //  63*512 shorts =  63 KB
  size_t af_bytes = ((size_t)NBLK + NLO) * 512 * sizeof(short);

  hipMemsetAsync(d_ws, 0, af_bytes, stream);         // zero OOR fragment slots
  prep_frags2<<<(124000 + 255)/256, 256, 0, stream>>>(W_msg, W_ih, W_hh, Wg, We,
                                                      AFhi, AFlo);
  mpnn_mfma<<<B_, TB, 0, stream>>>(nodes, edges, AFhi, AFlo, b_ih, b_hh, bg, be,
                                   Wo, bo, (float*)d_out);
}